// Round 4
// baseline (191.229 us; speedup 1.0000x reference)
//
#include <hip/hip_runtime.h>
#include <stdint.h>

#define NCOL 16
#define GRID 1024   // exactly 256 CU x 4 blocks/CU under launch_bounds(256,4)
#define NRED 32     // level-2 reducer blocks
typedef float v4f __attribute__((ext_vector_type(4)));

// Cross-block data movement uses ONLY relaxed agent-scope atomics (proven
// correct in an earlier round; they access the coherence point directly, no
// L2 writeback/invalidate). Ordering store->counter is by explicit
// s_waitcnt vmcnt(0) in the storing wave (wave 0 in every case below).
__device__ __forceinline__ void arrive_and_wait(uint32_t* ctr) {
    __syncthreads();                 // all waves' phase work complete
    if (threadIdx.x == 0) {
        // drain wave 0's outstanding agent-scope stores to the coherence
        // point BEFORE the arrival becomes visible (AITER-style counted wait)
        asm volatile("s_waitcnt vmcnt(0)" ::: "memory");
        __hip_atomic_fetch_add(ctr, 1u, __ATOMIC_RELAXED, __HIP_MEMORY_SCOPE_AGENT);
        while (__hip_atomic_load(ctr, __ATOMIC_RELAXED, __HIP_MEMORY_SCOPE_AGENT) < GRID)
            __builtin_amdgcn_s_sleep(2);
        asm volatile("" ::: "memory");
    }
    __syncthreads();
}

// out = w0*xn + w1*xn^2 + w2*xn^3 + w3*exp(xn) + w4*log(|xn|+1) + w5*sqrt(|xn|)
//     + w6*tanh(xn) + w7*sin(xn) + w8*|xn| + bias      (xn in [-1,1] -> clips no-op)
__device__ __forceinline__ float eval_basis(float xn, const float* w, float b) {
    float ax = fabsf(xn);
    float x2 = xn * xn;
    float x3 = x2 * xn;
    float e  = __expf(xn);
    float e2 = e * e;                               // exp(2*xn)
    float t  = 1.0f - 2.0f * __frcp_rn(e2 + 1.0f);  // tanh
    float l  = __logf(ax + 1.0f);
    float sq = __fsqrt_rn(ax);
    float sn = __sinf(xn);
    float r = b;
    r = fmaf(w[0], xn, r);
    r = fmaf(w[1], x2, r);
    r = fmaf(w[2], x3, r);
    r = fmaf(w[3], e,  r);
    r = fmaf(w[4], l,  r);
    r = fmaf(w[5], sq, r);
    r = fmaf(w[6], t,  r);
    r = fmaf(w[7], sn, r);
    r = fmaf(w[8], ax, r);
    return r;
}

// Single REGULAR-launch kernel (no cooperative API, graph-capture-safe):
//   P1: stream column min/max -> per-block 32 partials -> slots1[block][32]
//   B1 (spin barrier, counter 0)
//   P1.5: blocks 0..31 each reduce 32 slots1 rows -> slots2[b][32]  (wide, ~1us)
//   B2 (spin barrier, counter 1)
//   combine: every block reduces slots2[32][32] (4 KB) -> scale/off in LDS
//   P2: featurize (identical math to the proven 2-kernel version)
// Deadlock safety: GRID==capacity (256 CU x 4 blocks/CU), launch_bounds caps
// VGPR<=128, LDS ~1.7 KB -> all 1024 blocks co-resident.
__global__ void __launch_bounds__(256, 4) fused(const v4f* __restrict__ x,
                                                v4f* __restrict__ out,
                                                uint32_t* __restrict__ ctrs,   // [2], memset 0
                                                float* __restrict__ slots1,    // [GRID][32]
                                                float* __restrict__ slots2,    // [NRED][32]
                                                const float* __restrict__ wts,
                                                const float* __restrict__ bias,
                                                int n4) {
    __shared__ float smn[4][NCOL], smx[4][NCOL];
    __shared__ float s_red[8][32];
    __shared__ float s_scale[NCOL], s_off[NCOL], s_w[9];

    if (threadIdx.x < 9) s_w[threadIdx.x] = wts[threadIdx.x];

    const int tid = blockIdx.x * 256 + threadIdx.x;
    const int stride = GRID * 256;          // multiple of 4 -> column group fixed

    // ---- P1: streaming min/max (proven colreduce body) ----
    float mn0 = INFINITY, mn1 = INFINITY, mn2 = INFINITY, mn3 = INFINITY;
    float mx0 = -INFINITY, mx1 = -INFINITY, mx2 = -INFINITY, mx3 = -INFINITY;
    for (int i = tid; i < n4; i += stride) {
        v4f v = x[i];   // cached load: P2 re-reads the SAME addresses (L2 hits)
        mn0 = fminf(mn0, v.x); mx0 = fmaxf(mx0, v.x);
        mn1 = fminf(mn1, v.y); mx1 = fmaxf(mx1, v.y);
        mn2 = fminf(mn2, v.z); mx2 = fmaxf(mx2, v.z);
        mn3 = fminf(mn3, v.w); mx3 = fmaxf(mx3, v.w);
    }
    #pragma unroll
    for (int off = 4; off < 64; off <<= 1) {
        mn0 = fminf(mn0, __shfl_xor(mn0, off)); mx0 = fmaxf(mx0, __shfl_xor(mx0, off));
        mn1 = fminf(mn1, __shfl_xor(mn1, off)); mx1 = fmaxf(mx1, __shfl_xor(mx1, off));
        mn2 = fminf(mn2, __shfl_xor(mn2, off)); mx2 = fmaxf(mx2, __shfl_xor(mx2, off));
        mn3 = fminf(mn3, __shfl_xor(mn3, off)); mx3 = fmaxf(mx3, __shfl_xor(mx3, off));
    }
    int wave = threadIdx.x >> 6;
    int lane = threadIdx.x & 63;
    if (lane < 4) {           // lane l holds the full wave reduction for group l
        int g = lane * 4;
        smn[wave][g + 0] = mn0; smx[wave][g + 0] = mx0;
        smn[wave][g + 1] = mn1; smx[wave][g + 1] = mx1;
        smn[wave][g + 2] = mn2; smx[wave][g + 2] = mx2;
        smn[wave][g + 3] = mn3; smx[wave][g + 3] = mx3;
    }
    __syncthreads();
    if (threadIdx.x < NCOL) {     // wave 0 only -> vmcnt drain in barrier covers it
        int c = threadIdx.x;
        float m = fminf(fminf(smn[0][c], smn[1][c]), fminf(smn[2][c], smn[3][c]));
        float M = fmaxf(fmaxf(smx[0][c], smx[1][c]), fmaxf(smx[2][c], smx[3][c]));
        __hip_atomic_store(&slots1[(size_t)blockIdx.x * 32 + c],        m,
                           __ATOMIC_RELAXED, __HIP_MEMORY_SCOPE_AGENT);
        __hip_atomic_store(&slots1[(size_t)blockIdx.x * 32 + NCOL + c], M,
                           __ATOMIC_RELAXED, __HIP_MEMORY_SCOPE_AGENT);
    }
    arrive_and_wait(&ctrs[0]);

    // ---- P1.5: level-2 reduce, 32 blocks x 32 rows, fully parallel ----
    if (blockIdx.x < NRED) {
        int j  = threadIdx.x & 31;
        int r0 = threadIdx.x >> 5;                 // 8 row groups
        bool isMin = j < NCOL;
        float acc = isMin ? INFINITY : -INFINITY;
        #pragma unroll
        for (int r = r0; r < GRID / NRED; r += 8) {
            float v = __hip_atomic_load(
                &slots1[((size_t)blockIdx.x * (GRID / NRED) + r) * 32 + j],
                __ATOMIC_RELAXED, __HIP_MEMORY_SCOPE_AGENT);
            acc = isMin ? fminf(acc, v) : fmaxf(acc, v);
        }
        s_red[r0][j] = acc;
        __syncthreads();
        if (threadIdx.x < 32) {   // wave 0 -> vmcnt drain in barrier covers stores
            float a = s_red[0][j];
            #pragma unroll
            for (int g2 = 1; g2 < 8; ++g2)
                a = isMin ? fminf(a, s_red[g2][j]) : fmaxf(a, s_red[g2][j]);
            __hip_atomic_store(&slots2[(size_t)blockIdx.x * 32 + j], a,
                               __ATOMIC_RELAXED, __HIP_MEMORY_SCOPE_AGENT);
        }
    }
    arrive_and_wait(&ctrs[1]);

    // ---- combine: every block reduces slots2[NRED][32] (4 KB, L3-hot) ----
    {
        int j  = threadIdx.x & 31;
        int r0 = threadIdx.x >> 5;
        bool isMin = j < NCOL;
        float acc = isMin ? INFINITY : -INFINITY;
        #pragma unroll
        for (int r = r0; r < NRED; r += 8) {
            float v = __hip_atomic_load(&slots2[(size_t)r * 32 + j],
                                        __ATOMIC_RELAXED, __HIP_MEMORY_SCOPE_AGENT);
            acc = isMin ? fminf(acc, v) : fmaxf(acc, v);
        }
        s_red[r0][j] = acc;       // safe: B2's trailing __syncthreads passed
        __syncthreads();
        if (threadIdx.x < NCOL) {
            int c = threadIdx.x;
            float mn = INFINITY, mx = -INFINITY;
            #pragma unroll
            for (int g2 = 0; g2 < 8; ++g2) {
                mn = fminf(mn, s_red[g2][c]);
                mx = fmaxf(mx, s_red[g2][NCOL + c]);
            }
            float rr = mx - mn;
            if (rr == 0.0f) rr = 1.0f;
            s_scale[c] = 2.0f / rr;
            s_off[c]   = -2.0f * mn / rr - 1.0f;
        }
        __syncthreads();
    }

    // ---- P2: featurize (proven body) ----
    int g = (tid & 3) * 4;                 // this thread's 4 columns
    float sc0 = s_scale[g + 0], of0 = s_off[g + 0];
    float sc1 = s_scale[g + 1], of1 = s_off[g + 1];
    float sc2 = s_scale[g + 2], of2 = s_off[g + 2];
    float sc3 = s_scale[g + 3], of3 = s_off[g + 3];
    float w[9];
    #pragma unroll
    for (int k = 0; k < 9; ++k) w[k] = s_w[k];
    float b = bias[0];

    for (int i = tid; i < n4; i += stride) {
        v4f v = x[i];                      // same addrs as P1 -> partial L2 hits
        v4f o;
        o.x = eval_basis(fmaf(v.x, sc0, of0), w, b);
        o.y = eval_basis(fmaf(v.y, sc1, of1), w, b);
        o.z = eval_basis(fmaf(v.z, sc2, of2), w, b);
        o.w = eval_basis(fmaf(v.w, sc3, of3), w, b);
        // nontemporal: out is never re-read; don't evict x
        __builtin_nontemporal_store(o, &out[i]);
    }
}

extern "C" void kernel_launch(void* const* d_in, const int* in_sizes, int n_in,
                              void* d_out, int out_size, void* d_ws, size_t ws_size,
                              hipStream_t stream) {
    const v4f*   x    = (const v4f*)d_in[0];
    const float* wts  = (const float*)d_in[1];
    const float* bias = (const float*)d_in[2];
    v4f* out = (v4f*)d_out;

    uint32_t* ctrs   = (uint32_t*)d_ws;              // [2] barrier counters
    float*    slots1 = (float*)d_ws + 64;            // 256-B offset, [GRID][32]
    float*    slots2 = slots1 + (size_t)GRID * 32;   // [NRED][32], row-aligned

    int n  = in_sizes[0];       // N * 16 elements
    int n4 = n / 4;             // exact: 16e6 / 4

    // only the two barrier counters need init (ws is re-poisoned every iter)
    hipMemsetAsync(ctrs, 0, 2 * sizeof(uint32_t), stream);

    fused<<<GRID, 256, 0, stream>>>(x, out, ctrs, slots1, slots2, wts, bias, n4);
}

// Round 5
// 129.965 us; speedup vs baseline: 1.4714x; 1.4714x over previous
//
#include <hip/hip_runtime.h>
#include <stdint.h>

#define NCOL 16
#define NGRP 64   // atomic slot groups: contention per address = 1024/NGRP = 16
typedef float v4f __attribute__((ext_vector_type(4)));

// ---- ordered-uint mapping for float atomic min/max ----
// fkey is monotonic: a<b <=> fkey(a)<fkey(b).
// Min slot:  atomicMin(fkey(f)),  identity 0xFFFFFFFF.
// Max slot:  atomicMin(fkey(-f)), identity 0xFFFFFFFF  (order-reversed map),
//            decode as -fkey_dec(k).
// -> ALL slots share identity 0xFFFFFFFF: a single hipMemsetAsync.
__device__ __forceinline__ uint32_t fkey(float f) {
    uint32_t u = __float_as_uint(f);
    return (u & 0x80000000u) ? ~u : (u | 0x80000000u);
}
__device__ __forceinline__ float fkey_dec(uint32_t k) {
    uint32_t u = (k & 0x80000000u) ? (k ^ 0x80000000u) : ~k;
    return __uint_as_float(u);
}

// Column-wise min/max over x[N,16] row-major, read as float4.
// mm layout: [NGRP][32] u32 -- per-group {minkey[16], maxkey[16]}.
// Grid 1024 (vs round-2's 2048): half the blocks to schedule, half the
// epilogue atomics (16 same-address RMWs/slot); 262k threads with 4
// independent loads in flight still saturate the read stream.
__global__ void __launch_bounds__(256) colreduce(const v4f* __restrict__ x,
                                                 uint32_t* __restrict__ mm, int n4) {
    int tid = blockIdx.x * blockDim.x + threadIdx.x;
    int stride = gridDim.x * blockDim.x;   // 256-thread blocks -> multiple of 4
    float mn0 = INFINITY, mn1 = INFINITY, mn2 = INFINITY, mn3 = INFINITY;
    float mx0 = -INFINITY, mx1 = -INFINITY, mx2 = -INFINITY, mx3 = -INFINITY;
    #pragma unroll 4
    for (int i = tid; i < n4; i += stride) {
        v4f v = x[i];   // regular load: populates L2/L3 so pass 2 hits L3
        mn0 = fminf(mn0, v.x); mx0 = fmaxf(mx0, v.x);
        mn1 = fminf(mn1, v.y); mx1 = fmaxf(mx1, v.y);
        mn2 = fminf(mn2, v.z); mx2 = fmaxf(mx2, v.z);
        mn3 = fminf(mn3, v.w); mx3 = fmaxf(mx3, v.w);
    }
    // Butterfly across the 16 lanes sharing the same (lane&3) column group.
    #pragma unroll
    for (int off = 4; off < 64; off <<= 1) {
        mn0 = fminf(mn0, __shfl_xor(mn0, off)); mx0 = fmaxf(mx0, __shfl_xor(mx0, off));
        mn1 = fminf(mn1, __shfl_xor(mn1, off)); mx1 = fmaxf(mx1, __shfl_xor(mx1, off));
        mn2 = fminf(mn2, __shfl_xor(mn2, off)); mx2 = fmaxf(mx2, __shfl_xor(mx2, off));
        mn3 = fminf(mn3, __shfl_xor(mn3, off)); mx3 = fmaxf(mx3, __shfl_xor(mx3, off));
    }
    __shared__ float smn[4][NCOL], smx[4][NCOL];
    int wave = threadIdx.x >> 6;
    int lane = threadIdx.x & 63;
    if (lane < 4) {           // lane l holds the full wave reduction for group l
        int g = lane * 4;
        smn[wave][g + 0] = mn0; smx[wave][g + 0] = mx0;
        smn[wave][g + 1] = mn1; smx[wave][g + 1] = mx1;
        smn[wave][g + 2] = mn2; smx[wave][g + 2] = mx2;
        smn[wave][g + 3] = mn3; smx[wave][g + 3] = mx3;
    }
    __syncthreads();
    if (threadIdx.x < NCOL) {
        int c = threadIdx.x;
        float m = fminf(fminf(smn[0][c], smn[1][c]), fminf(smn[2][c], smn[3][c]));
        float M = fmaxf(fmaxf(smx[0][c], smx[1][c]), fmaxf(smx[2][c], smx[3][c]));
        uint32_t* grp = mm + (size_t)(blockIdx.x & (NGRP - 1)) * 32;
        atomicMin(&grp[c], fkey(m));
        atomicMin(&grp[NCOL + c], fkey(-M));   // reversed map: max via atomicMin
    }
}

// out = w0*xn + w1*xn^2 + w2*xn^3 + w3*exp(xn) + w4*log(|xn|+1) + w5*sqrt(|xn|)
//     + w6*tanh(xn) + w7*sin(xn) + w8*|xn| + bias      (xn in [-1,1] -> clips no-op)
__device__ __forceinline__ float eval_basis(float xn, const float* w, float b) {
    float ax = fabsf(xn);
    float x2 = xn * xn;
    float x3 = x2 * xn;
    float e  = __expf(xn);
    float e2 = e * e;                               // exp(2*xn)
    float t  = 1.0f - 2.0f * __frcp_rn(e2 + 1.0f);  // tanh
    float l  = __logf(ax + 1.0f);
    float sq = __fsqrt_rn(ax);
    float sn = __sinf(xn);
    float r = b;
    r = fmaf(w[0], xn, r);
    r = fmaf(w[1], x2, r);
    r = fmaf(w[2], x3, r);
    r = fmaf(w[3], e,  r);
    r = fmaf(w[4], l,  r);
    r = fmaf(w[5], sq, r);
    r = fmaf(w[6], t,  r);
    r = fmaf(w[7], sn, r);
    r = fmaf(w[8], ax, r);
    return r;
}

__global__ void __launch_bounds__(256) feature_kernel(const v4f* __restrict__ x,
                                                      v4f* __restrict__ out,
                                                      const uint32_t* __restrict__ mm,
                                                      const float* __restrict__ wts,
                                                      const float* __restrict__ bias,
                                                      int n4) {
    // Combine the NGRP partial-key groups in parallel: thread t reduces
    // column j = t&31 over 8 rows (coalesced 128-B row reads, L2-hot).
    __shared__ uint32_t s_part[8][32];
    __shared__ float s_scale[NCOL], s_off[NCOL], s_w[9];
    {
        int j = threadIdx.x & 31;
        int r0 = threadIdx.x >> 5;            // 8 row groups
        uint32_t k = 0xFFFFFFFFu;
        #pragma unroll
        for (int r = 0; r < NGRP / 8; ++r)
            k = min(k, mm[(size_t)(r * 8 + r0) * 32 + j]);
        s_part[r0][j] = k;
    }
    if (threadIdx.x < 9) s_w[threadIdx.x] = wts[threadIdx.x];
    __syncthreads();
    if (threadIdx.x < NCOL) {
        int c = threadIdx.x;
        uint32_t kmn = s_part[0][c], kmx = s_part[0][NCOL + c];
        #pragma unroll
        for (int g2 = 1; g2 < 8; ++g2) {
            kmn = min(kmn, s_part[g2][c]);
            kmx = min(kmx, s_part[g2][NCOL + c]);
        }
        float mn = fkey_dec(kmn);
        float mx = -fkey_dec(kmx);              // reversed-map decode
        float r = mx - mn;
        if (r == 0.0f) r = 1.0f;
        s_scale[c] = 2.0f / r;
        s_off[c]   = -2.0f * mn / r - 1.0f;
    }
    __syncthreads();

    int tid = blockIdx.x * blockDim.x + threadIdx.x;
    int stride = gridDim.x * blockDim.x;   // multiple of 4 -> column group fixed
    int g = (tid & 3) * 4;                 // this thread's 4 columns
    float sc0 = s_scale[g + 0], of0 = s_off[g + 0];
    float sc1 = s_scale[g + 1], of1 = s_off[g + 1];
    float sc2 = s_scale[g + 2], of2 = s_off[g + 2];
    float sc3 = s_scale[g + 3], of3 = s_off[g + 3];
    float w[9];
    #pragma unroll
    for (int k = 0; k < 9; ++k) w[k] = s_w[k];
    float b = bias[0];

    for (int i = tid; i < n4; i += stride) {
        v4f v = x[i];
        v4f o;
        o.x = eval_basis(fmaf(v.x, sc0, of0), w, b);
        o.y = eval_basis(fmaf(v.y, sc1, of1), w, b);
        o.z = eval_basis(fmaf(v.z, sc2, of2), w, b);
        o.w = eval_basis(fmaf(v.w, sc3, of3), w, b);
        // nontemporal: out is never re-read; don't evict x from L2/L3
        __builtin_nontemporal_store(o, &out[i]);
    }
}

extern "C" void kernel_launch(void* const* d_in, const int* in_sizes, int n_in,
                              void* d_out, int out_size, void* d_ws, size_t ws_size,
                              hipStream_t stream) {
    const float* x    = (const float*)d_in[0];
    const float* wts  = (const float*)d_in[1];
    const float* bias = (const float*)d_in[2];
    float* out = (float*)d_out;
    uint32_t* mm = (uint32_t*)d_ws;     // [NGRP][32] keys

    int n  = in_sizes[0];       // N * 16 elements
    int n4 = n / 4;             // exact: 16e6 / 4

    // single init: every slot's identity is 0xFFFFFFFF (see fkey comment)
    hipMemsetAsync(mm, 0xFF, (size_t)NGRP * 32 * sizeof(uint32_t), stream);

    colreduce<<<1024, 256, 0, stream>>>((const v4f*)x, mm, n4);
    feature_kernel<<<2048, 256, 0, stream>>>((const v4f*)x, (v4f*)out, mm,
                                             wts, bias, n4);
}